// Round 7
// baseline (20.562 us; speedup 1.0000x reference)
//
#include <hip/hip_runtime.h>
#include <hip/hip_bf16.h>

#define LEN   16384
#define NB    128
#define LOUT  16513   // LEN + 2*128 - 128 + 1
#define SENT  0x5A5A5A5Au

typedef __attribute__((ext_vector_type(8))) short bf16x8;
typedef __attribute__((ext_vector_type(4))) float f32x4;

__device__ __forceinline__ unsigned short f2bf(float f) {
    union { float f; unsigned u; } c; c.f = f;
    unsigned r = c.u + 0x7FFF + ((c.u >> 16) & 1);   // RNE
    return (unsigned short)(r >> 16);
}
__device__ __forceinline__ unsigned packbf2(float lo, float hi) {
    __hip_bfloat162 p = __float22bfloat162_rn(make_float2(lo, hi));
    union { __hip_bfloat162 h; unsigned u; } c; c.h = p;
    return c.u;
}

template<bool CHECK>
__device__ __forceinline__ float4 ldx4(const float4* __restrict__ xr4, int i) {
    if (CHECK) {
        float4 v = make_float4(0.f, 0.f, 0.f, 0.f);
        if ((unsigned)i < 4096u) v = xr4[i];
        return v;
    }
    return xr4[i];
}

template<bool CHECK>
__device__ __forceinline__ void do_tile(const float4* __restrict__ xr4,
                                        const bf16x8* afA, const bf16x8* afB,
                                        int g4base, f32x4& aA, f32x4& aB) {
    #pragma unroll
    for (int kb = 0; kb < 5; ++kb) {
        float4 vlo = ldx4<CHECK>(xr4, g4base + 8 * kb);
        float4 vhi = ldx4<CHECK>(xr4, g4base + 8 * kb + 4);
        union { bf16x8 v8; unsigned u[4]; } bu;
        bu.u[0] = packbf2(vlo.x, vlo.y);
        bu.u[1] = packbf2(vlo.z, vlo.w);
        bu.u[2] = packbf2(vhi.x, vhi.y);
        bu.u[3] = packbf2(vhi.z, vhi.w);
        aA = __builtin_amdgcn_mfma_f32_16x16x32_bf16(afA[kb], bu.v8, aA, 0, 0, 0);
        aB = __builtin_amdgcn_mfma_f32_16x16x32_bf16(afB[kb], bu.v8, aB, 0, 0, 0);
    }
}

// y[b,t] = sum_k filt[b,k]*xp[b,t+k], xp[i]=x[i-128] zero-padded
// filt = A_b + Sb*B;  A_b = fc_b + H - (xl*G0 + x0*G2)/L;  B = (G0+G1+G2)/L
__global__ __launch_bounds__(512) void fused_fir(
    const float* __restrict__ x, const float* __restrict__ conv_w,
    const float* __restrict__ conv_b, const float* __restrict__ fc_w,
    const float* __restrict__ fc_b, float* __restrict__ out,
    float* __restrict__ wsum, unsigned* __restrict__ wflag)
{
    const int id  = blockIdx.x;
    const int b   = id & (NB - 1);
    const int h   = id >> 7;            // output half; pair (b,h=0/1) shares an XCD
    const int tid = threadIdx.x;

    __shared__ float    scwb[512];      // conv_w[384] ++ conv_b[128]
    __shared__ unsigned fpAB[288];      // packed {A(lo16),B(hi16)} bf16, padded shifted filter
    __shared__ float    parts[8];
    __shared__ float    sSb;

    const float*  xr  = x + (size_t)b * LEN;
    const float4* xr4 = reinterpret_cast<const float4*>(xr);
    const float4* fw4 = reinterpret_cast<const float4*>(fc_w);

    // ---- issue loads, oldest-first (vmcnt is in-order per wave) ----
    const float x0 = xr[0];
    const float xl = xr[LEN - 1];
    const float* csrc = (tid < 384) ? (conv_w + tid) : (conv_b + tid - 384);
    const float cstage = *csrc;
    const int t = tid >> 2, q = tid & 3;
    const float fcb = fc_b[t];
    float4 fw[8];
    #pragma unroll
    for (int m = 0; m < 8; ++m) fw[m] = fw4[32 * t + 8 * q + m];
    float4 rv[4];                        // OWN HALF of the row only (32 KB/block)
    #pragma unroll
    for (int p = 0; p < 4; ++p) rv[p] = xr4[2048 * h + tid + 512 * p];

    // ---- stage conv into LDS; barrier #0 (lgkm only — row loads stay in flight) ----
    scwb[tid] = cstage;
    asm volatile("s_waitcnt lgkmcnt(0)" ::: "memory");
    __builtin_amdgcn_s_barrier();
    asm volatile("" ::: "memory");

    // ---- G matvec partials over c in [32q,32q+32) (LDS + regs only) ----
    float g0 = 0.f, g1 = 0.f, g2 = 0.f, hh = 0.f;
    const float4* scw4 = reinterpret_cast<const float4*>(scwb);
    #pragma unroll
    for (int m = 0; m < 8; ++m) {
        const float4 cwA = scw4[24 * q + 3 * m + 0];
        const float4 cwB = scw4[24 * q + 3 * m + 1];
        const float4 cwC = scw4[24 * q + 3 * m + 2];
        const float4 cb  = scw4[96 + 8 * q + m];
        const float f0 = fw[m].x, f1 = fw[m].y, f2 = fw[m].z, f3 = fw[m].w;
        g0 = fmaf(f0, cwA.x, fmaf(f1, cwA.w, fmaf(f2, cwB.z, fmaf(f3, cwC.y, g0))));
        g1 = fmaf(f0, cwA.y, fmaf(f1, cwB.x, fmaf(f2, cwB.w, fmaf(f3, cwC.z, g1))));
        g2 = fmaf(f0, cwA.z, fmaf(f1, cwB.y, fmaf(f2, cwC.x, fmaf(f3, cwC.w, g2))));
        hh = fmaf(f0, cb.x,  fmaf(f1, cb.y,  fmaf(f2, cb.z,  fmaf(f3, cb.w,  hh))));
    }
    g0 += __shfl_xor(g0, 1); g0 += __shfl_xor(g0, 2);
    g1 += __shfl_xor(g1, 1); g1 += __shfl_xor(g1, 2);
    g2 += __shfl_xor(g2, 1); g2 += __shfl_xor(g2, 2);
    hh += __shfl_xor(hh, 1); hh += __shfl_xor(hh, 2);

    if (q == 0) {
        const float invL = 1.0f / (float)LEN;
        const float A = fcb + hh - invL * fmaf(xl, g0, x0 * g2);
        const float B = invL * ((g0 + g1) + g2);
        fpAB[128 + t] = (unsigned)f2bf(A) | ((unsigned)f2bf(B) << 16);
    }
    if (q == 1) fpAB[t] = 0u;                   // [0,128)
    if (q == 2 && t < 32) fpAB[256 + t] = 0u;   // [256,288)

    // ---- own-half row sum (rv arrived during G matvec) ----
    const int l = tid & 63, w = tid >> 6;
    float s = 0.f;
    #pragma unroll
    for (int p = 0; p < 4; ++p) s += (rv[p].x + rv[p].y) + (rv[p].z + rv[p].w);
    #pragma unroll
    for (int off = 32; off > 0; off >>= 1) s += __shfl_down(s, off, 64);
    if (l == 0) parts[w] = s;

    // ---- barrier #1: filters + parts visible; publish half-sum ----
    asm volatile("s_waitcnt lgkmcnt(0)" ::: "memory");
    __builtin_amdgcn_s_barrier();
    asm volatile("" ::: "memory");

    float sb_own = 0.f;
    if (tid == 0) {
        #pragma unroll
        for (int i = 0; i < 8; ++i) sb_own += parts[i];
        __hip_atomic_store(&wsum[2 * b + h], sb_own,
                           __ATOMIC_RELAXED, __HIP_MEMORY_SCOPE_AGENT);
        __hip_atomic_store(&wflag[2 * b + h], SENT,
                           __ATOMIC_RELEASE, __HIP_MEMORY_SCOPE_AGENT);
    }

    // ---- build A/B fragments (Toeplitz shift) ----
    const int n = l & 15, g = l >> 4;
    bf16x8 afA[5], afB[5];
    #pragma unroll
    for (int kb = 0; kb < 5; ++kb)
        #pragma unroll
        for (int hf = 0; hf < 2; ++hf)
            #pragma unroll
            for (int j = 0; j < 4; ++j) {
                const unsigned v = fpAB[128 + 32 * kb + 16 * hf + 4 * g + j - n];
                afA[kb][hf * 4 + j] = (short)(v & 0xFFFFu);
                afB[kb][hf * 4 + j] = (short)(v >> 16);
            }

    // ---- MFMA FIR, x read direct from global (L1/L2-hot) ----
    const int Tlim = h ? 65 : 33;
    f32x4 accA[5], accB[5];
    #pragma unroll
    for (int it = 0; it < 5; ++it) {
        const int T = 33 * h + w + 8 * it;
        if (T < Tlim) {
            const int g4base = (256 * T + 16 * n + 4 * g - 128) >> 2;
            f32x4 aA = {0.f, 0.f, 0.f, 0.f}, aB = {0.f, 0.f, 0.f, 0.f};
            if (T == 0 || T >= 63) do_tile<true >(xr4, afA, afB, g4base, aA, aB);
            else                   do_tile<false>(xr4, afA, afB, g4base, aA, aB);
            accA[it] = aA; accB[it] = aB;
        }
    }

    // ---- fetch partner half-sum (published long ago), barrier #2, combine ----
    if (tid == 0) {
        const int p = 2 * b + (1 - h);
        while (__hip_atomic_load(&wflag[p], __ATOMIC_ACQUIRE,
                                 __HIP_MEMORY_SCOPE_AGENT) != SENT)
            __builtin_amdgcn_s_sleep(1);
        const float so = __hip_atomic_load(&wsum[p], __ATOMIC_RELAXED,
                                           __HIP_MEMORY_SCOPE_AGENT);
        sSb = sb_own + so;
    }
    asm volatile("s_waitcnt lgkmcnt(0)" ::: "memory");
    __builtin_amdgcn_s_barrier();
    asm volatile("" ::: "memory");
    const float Sb = sSb;

    // ---- combine y = accA + Sb*accB and store ----
    float* orow = out + (size_t)b * LOUT;
    #pragma unroll
    for (int it = 0; it < 5; ++it) {
        const int T = 33 * h + w + 8 * it;
        if (T < Tlim) {
            f32x4 y;
            #pragma unroll
            for (int j = 0; j < 4; ++j) y[j] = fmaf(Sb, accB[it][j], accA[it][j]);
            const int t0 = 256 * T + 16 * n + 4 * g;
            if (T < 64) {
                *reinterpret_cast<f32x4*>(&orow[t0]) = y;
            } else {
                #pragma unroll
                for (int j = 0; j < 4; ++j)
                    if (t0 + j < LOUT) orow[t0 + j] = y[j];
            }
        }
    }
}

extern "C" void kernel_launch(void* const* d_in, const int* in_sizes, int n_in,
                              void* d_out, int out_size, void* d_ws, size_t ws_size,
                              hipStream_t stream)
{
    const float* x      = (const float*)d_in[0];
    const float* conv_w = (const float*)d_in[1];
    const float* conv_b = (const float*)d_in[2];
    const float* fc_w   = (const float*)d_in[3];
    const float* fc_b   = (const float*)d_in[4];
    float* out = (float*)d_out;
    float*    wsum  = (float*)d_ws;                       // 256 floats
    unsigned* wflag = (unsigned*)((char*)d_ws + 4096);    // 256 flags

    fused_fir<<<dim3(2 * NB), 512, 0, stream>>>(x, conv_w, conv_b, fc_w, fc_b,
                                                out, wsum, wflag);
}

// Round 8
// 17.980 us; speedup vs baseline: 1.1436x; 1.1436x over previous
//
#include <hip/hip_runtime.h>

#define LEN   16384
#define NB    128
#define NTAPS 128
#define LOUT  16513          // LEN + 2*128 - 128 + 1
#define NT    33             // 256-output tiles per block (2 blocks per batch)
#define SPAN  (NT*256 + 144) // 8592 floats of xp staged per block

typedef __attribute__((ext_vector_type(8))) short bf16x8;
typedef __attribute__((ext_vector_type(4))) float f32x4;

__device__ __forceinline__ unsigned short f2bf(float f) {
    union { float f; unsigned u; } c; c.f = f;
    unsigned r = c.u + 0x7FFF + ((c.u >> 16) & 1);   // RNE
    return (unsigned short)(r >> 16);
}

__global__ __launch_bounds__(512) void fused_fir(
    const float* __restrict__ x, const float* __restrict__ conv_w,
    const float* __restrict__ conv_b, const float* __restrict__ fc_w,
    const float* __restrict__ fc_b, float* __restrict__ out)
{
    const int b   = blockIdx.y;
    const int h   = blockIdx.x;          // 0: outputs [0,8448), 1: [8448,16513)
    const int tid = threadIdx.x;

    __shared__ unsigned short sxp[SPAN]; // xp tile, bf16
    __shared__ unsigned short fp[288];   // padded shifted filter, bf16; fp[j]=filt[j-128]
    __shared__ float scw[384];           // conv_w
    __shared__ float scb[128];           // conv_b
    __shared__ float sfb[128];           // fc_b
    __shared__ float parts[8];
    __shared__ float sx0, sxl;

    const float* xr  = x + (size_t)b * LEN;
    const float4* xr4 = reinterpret_cast<const float4*>(xr);

    // ---- stage small weight arrays ----
    if (tid < 384) scw[tid] = conv_w[tid];
    else if (tid < 512) scb[tid - 384] = conv_b[tid - 384];
    if (tid < 128) sfb[tid] = fc_b[tid];
    if (tid == 0) { sx0 = xr[0]; sxl = xr[LEN - 1]; }

    // ---- full-row read: sum + bf16-stage this block's xp span ----
    // span float s corresponds to xp[P0+s], P0 = 8448*h; xp[i] = x[i-128] (zero-pad).
    // float4: s4 = g4 + 32 - 2112*h
    float s = 0.f;
    const int sbase = 32 - 2112 * h;
    #pragma unroll
    for (int p = 0; p < 8; ++p) {
        const int g4 = tid + p * 512;
        float4 v = xr4[g4];
        s += (v.x + v.y) + (v.z + v.w);
        const int s4 = g4 + sbase;
        if (s4 >= 0 && s4 < SPAN / 4) {
            ushort4 hv;
            hv.x = f2bf(v.x); hv.y = f2bf(v.y); hv.z = f2bf(v.z); hv.w = f2bf(v.w);
            *reinterpret_cast<ushort4*>(&sxp[4 * s4]) = hv;
        }
    }
    // zero-fill span pads
    {
        const ushort4 z = {0, 0, 0, 0};
        if (h == 0) {
            if (tid < 32) *reinterpret_cast<ushort4*>(&sxp[4 * tid]) = z;
        } else {
            if (tid < 132) *reinterpret_cast<ushort4*>(&sxp[4 * (2016 + tid)]) = z;
        }
    }

    // ---- fc_w loads for G computation (4 threads per tap t) ----
    const int t = tid >> 2, q = tid & 3;
    const float4* fw4 = reinterpret_cast<const float4*>(fc_w);
    float4 fw[8];
    #pragma unroll
    for (int m = 0; m < 8; ++m) fw[m] = fw4[8 * tid + m];

    // ---- block-wide row sum ----
    #pragma unroll
    for (int off = 32; off > 0; off >>= 1) s += __shfl_down(s, off, 64);
    if ((tid & 63) == 0) parts[tid >> 6] = s;
    __syncthreads();
    float Sb = 0.f;
    #pragma unroll
    for (int i = 0; i < 8; ++i) Sb += parts[i];

    // ---- G0,G1,G2,H partials over c in [32q, 32q+32) ----
    float g0 = 0.f, g1 = 0.f, g2 = 0.f, hh = 0.f;
    #pragma unroll
    for (int m = 0; m < 8; ++m) {
        const float fv[4] = {fw[m].x, fw[m].y, fw[m].z, fw[m].w};
        #pragma unroll
        for (int jj = 0; jj < 4; ++jj) {
            const int c = 32 * q + 4 * m + jj;
            const float f = fv[jj];
            g0 = fmaf(f, scw[3 * c + 0], g0);
            g1 = fmaf(f, scw[3 * c + 1], g1);
            g2 = fmaf(f, scw[3 * c + 2], g2);
            hh = fmaf(f, scb[c], hh);
        }
    }
    g0 += __shfl_xor(g0, 1); g0 += __shfl_xor(g0, 2);
    g1 += __shfl_xor(g1, 1); g1 += __shfl_xor(g1, 2);
    g2 += __shfl_xor(g2, 1); g2 += __shfl_xor(g2, 2);
    hh += __shfl_xor(hh, 1); hh += __shfl_xor(hh, 2);

    if (q == 0) {
        const float invL = 1.0f / (float)LEN;
        const float flt = sfb[t] + hh
            + invL * fmaf(Sb - sxl, g0, fmaf(Sb, g1, (Sb - sx0) * g2));
        fp[128 + t] = f2bf(flt);
    }
    if (q == 1) fp[t] = 0;
    if (q == 2 && t < 32) fp[256 + t] = 0;
    __syncthreads();

    // ---- build A fragments (shifted filter) ----
    const int l = tid & 63, w = tid >> 6;
    const int n = l & 15;        // C-col
    const int g = l >> 4;        // k-group
    bf16x8 afrag[5];
    #pragma unroll
    for (int kb = 0; kb < 5; ++kb)
        #pragma unroll
        for (int hf = 0; hf < 2; ++hf)
            #pragma unroll
            for (int j = 0; j < 4; ++j)
                afrag[kb][hf * 4 + j] =
                    (short)fp[128 + 32 * kb + 16 * hf + 4 * g + j - n];

    // ---- MFMA FIR: wave w handles tiles tau = w + 8*it ----
    float* orow = out + (size_t)b * LOUT;
    #pragma unroll
    for (int it = 0; it < 5; ++it) {
        const int tau = w + 8 * it;
        if (tau >= NT) break;                 // wave-uniform
        const int T = h * NT + tau;           // global tile index
        if (T >= 65) break;                   // T=65 starts past LOUT
        const unsigned short* bp = &sxp[tau * 256 + 16 * n + 4 * g];
        f32x4 acc = {0.f, 0.f, 0.f, 0.f};
        #pragma unroll
        for (int kb = 0; kb < 5; ++kb) {
            ushort4 lo = *reinterpret_cast<const ushort4*>(bp + 32 * kb);
            ushort4 hi = *reinterpret_cast<const ushort4*>(bp + 32 * kb + 16);
            bf16x8 bfrag;
            bfrag[0] = (short)lo.x; bfrag[1] = (short)lo.y;
            bfrag[2] = (short)lo.z; bfrag[3] = (short)lo.w;
            bfrag[4] = (short)hi.x; bfrag[5] = (short)hi.y;
            bfrag[6] = (short)hi.z; bfrag[7] = (short)hi.w;
            acc = __builtin_amdgcn_mfma_f32_16x16x32_bf16(afrag[kb], bfrag, acc, 0, 0, 0);
        }
        const int t0 = 256 * T + 16 * n + 4 * g;
        if (T < 64) {
            orow[t0 + 0] = acc[0];
            orow[t0 + 1] = acc[1];
            orow[t0 + 2] = acc[2];
            orow[t0 + 3] = acc[3];
        } else {
            #pragma unroll
            for (int j = 0; j < 4; ++j)
                if (t0 + j < LOUT) orow[t0 + j] = acc[j];
        }
    }
}

extern "C" void kernel_launch(void* const* d_in, const int* in_sizes, int n_in,
                              void* d_out, int out_size, void* d_ws, size_t ws_size,
                              hipStream_t stream)
{
    const float* x      = (const float*)d_in[0];
    const float* conv_w = (const float*)d_in[1];
    const float* conv_b = (const float*)d_in[2];
    const float* fc_w   = (const float*)d_in[3];
    const float* fc_b   = (const float*)d_in[4];
    float* out = (float*)d_out;

    dim3 grid(2, NB);   // 2 half-row blocks per batch
    fused_fir<<<grid, 512, 0, stream>>>(x, conv_w, conv_b, fc_w, fc_b, out);
}